// Round 10
// baseline (115.952 us; speedup 1.0000x reference)
//
#include <hip/hip_runtime.h>

// UPCLoss, algebraically reduced (validated R7-R9, absmax 0.0):
//   N^2*loss = sum_i u_i*||x_i||^2 - 2 * sum_{c,k} W[c][k]*S[c][k]
//   [W;S] = [G2 | onehot]^T (32x512) . X (512x65536)  (tall-skinny GEMM)
//   u_i   = sum_c cnt[c]*G2[i][c] + H[label_i],  H[c] = sum_i G2[i][c]
// R8/R9 were killed by 256KB-strided dword gathers (~750 GB/s cap).
// This version: coalesced global_load_lds staging -> LDS -> MFMA.

typedef float f32x4 __attribute__((ext_vector_type(4)));
typedef __bf16 bf16x8 __attribute__((ext_vector_type(8)));

constexpr int NROW = 512;
constexpr int KDIM = 65536;

__device__ __forceinline__ unsigned short bf16_bits(float v) {
    __bf16 h = (__bf16)v;
    unsigned short u;
    __builtin_memcpy(&u, &h, 2);
    return u;
}

__device__ __forceinline__ void gload16(const void* g, void* l) {
    __builtin_amdgcn_global_load_lds(
        (__attribute__((address_space(1))) void*)(g),
        (__attribute__((address_space(3))) void*)(l), 16, 0, 0);
}

// ---------- prep (identical to R9, validated) ----------
// g2a/g2s: MFMA A-fragment tables [16 steps][64 lanes][8] bf16
//   g2a[(s*64+l)*8+t] = G2[s*32+(l>>4)*8+t][l&15]; g2s with onehot.
__global__ __launch_bounds__(512) void prep_kernel(const int* __restrict__ ranking,
                                                   const int* __restrict__ choice,
                                                   const int* __restrict__ ncp,
                                                   unsigned short* __restrict__ g2a,
                                                   unsigned short* __restrict__ g2s,
                                                   float* __restrict__ utab) {
    __shared__ float Hs[16];
    __shared__ int   cnt[16];
    int i = threadIdx.x;
    if (i < 16) { Hs[i] = 0.f; cnt[i] = 0; }
    __syncthreads();

    int rk[16];
#pragma unroll
    for (int q = 0; q < 16; ++q) rk[q] = ranking[i * 16 + q];
    int pos[16];
#pragma unroll
    for (int q = 0; q < 16; ++q) pos[rk[q]] = q;

    int   lbl = rk[0];
    float c   = (float)choice[i];
    float nc  = (float)(*ncp);
    atomicAdd(&cnt[lbl], 1);

    float grow[16];
#pragma unroll
    for (int q = 0; q < 16; ++q) {
        float r = (float)pos[q];
        float m = (r < c) ? (1.f - r / c) : (-(r - c + 1.f) / (nc - c));
        grow[q] = m * m;
        atomicAdd(&Hs[q], grow[q]);
    }

    int s = i >> 5, g = (i >> 3) & 3, t = i & 7;
#pragma unroll
    for (int q = 0; q < 16; ++q) {
        int idx = (s * 64 + (g << 4) + q) * 8 + t;
        g2a[idx] = bf16_bits(grow[q]);
        g2s[idx] = bf16_bits(q == lbl ? 1.f : 0.f);
    }
    __syncthreads();

    float u = 0.f;
#pragma unroll
    for (int q = 0; q < 16; ++q) u += (float)cnt[q] * grow[q];
    u += Hs[lbl];
    utab[i] = u;
}

// stage one 32x64 fp32 chunk (rows [s*32,+32), cols [blk*64,+64)) into LDS.
// Coalesced: 16 lanes x 16B = 256B contiguous per row; 2 instrs/thread.
__device__ __forceinline__ void stage_step(const float* __restrict__ X, int blk,
                                           int s, float* buf, int lane, int wv) {
#pragma unroll
    for (int g = 0; g < 2; ++g) {
        int r = wv * 8 + g * 4 + (lane >> 4);
        const float* gsrc = X + (size_t)(s * 32 + r) * KDIM + blk * 64 + (lane & 15) * 4;
        char* ldst = (char*)buf + (wv * 8 + g * 4) * 256;   // + lane*16 by HW
        gload16(gsrc, ldst);
    }
}

// ---------- main pass: 1024 blocks x 4 waves; block owns 64 columns ----------
__global__ __launch_bounds__(256, 4) void colpass(const float* __restrict__ X,
                                                  const unsigned short* __restrict__ g2a,
                                                  const unsigned short* __restrict__ g2s,
                                                  const float* __restrict__ utab,
                                                  float* __restrict__ acc) {
    __shared__ __align__(16) float lds[2][32 * 64];   // 2 x 8 KB

    int t    = threadIdx.x;
    int lane = t & 63;
    int wv   = t >> 6;                 // wave = colgroup 0..3
    int blk  = blockIdx.x;
    int rg   = lane >> 4;
    int cl   = wv * 16 + (lane & 15);  // local column for B-fragment
    int trow = t >> 3, tc = (t & 7) * 8;   // t1-term assignment (8 elems/thread)

    f32x4 accw = {};
    f32x4 accs = {};
    float t1 = 0.f;

    stage_step(X, blk, 0, &lds[0][0], lane, wv);
    __syncthreads();

    for (int s = 0; s < 16; ++s) {
        int cur = s & 1;
        if (s < 15) stage_step(X, blk, s + 1, &lds[cur ^ 1][0], lane, wv);

        const float* cb = &lds[cur][0];

        // B-fragment: x[s*32 + rg*8 + tt][blk*64 + cl]
        float xv[8];
#pragma unroll
        for (int tt = 0; tt < 8; ++tt)
            xv[tt] = cb[(rg * 8 + tt) * 64 + cl];
        bf16x8 xb;
#pragma unroll
        for (int tt = 0; tt < 8; ++tt) xb[tt] = (__bf16)xv[tt];

        bf16x8 aw = *reinterpret_cast<const bf16x8*>(g2a + (s * 64 + lane) * 8);
        bf16x8 as = *reinterpret_cast<const bf16x8*>(g2s + (s * 64 + lane) * 8);

        accw = __builtin_amdgcn_mfma_f32_16x16x32_bf16(aw, xb, accw, 0, 0, 0);
        accs = __builtin_amdgcn_mfma_f32_16x16x32_bf16(as, xb, accs, 0, 0, 0);

        // t1 += u[row] * sum(x^2) over this thread's 8 staged elements
        const float4* tv = reinterpret_cast<const float4*>(cb + trow * 64 + tc);
        float4 v0 = tv[0], v1 = tv[1];
        float  u  = utab[s * 32 + trow];
        float  ss = v0.x * v0.x + v0.y * v0.y + v0.z * v0.z + v0.w * v0.w
                  + v1.x * v1.x + v1.y * v1.y + v1.z * v1.z + v1.w * v1.w;
        t1 = fmaf(u, ss, t1);

        __syncthreads();   // next buffer staged & visible; cur free for s+2
    }

    // lane holds W[c][j],S[c][j] for c=(lane>>4)*4+v, j = blk*64+cl — each
    // (c,j) in exactly one lane devicewide: fold locally, one atomic per wave.
    float cross = accw[0] * accs[0] + accw[1] * accs[1]
                + accw[2] * accs[2] + accw[3] * accs[3];
    float local = fmaf(-2.f, cross, t1);

#pragma unroll
    for (int off = 32; off > 0; off >>= 1) local += __shfl_down(local, off);
    if (lane == 0) atomicAdd(acc, local);
}

__global__ void finalize(const float* __restrict__ acc, float* __restrict__ out) {
    out[0] = acc[0] * (1.f / ((float)NROW * (float)NROW));
}

extern "C" void kernel_launch(void* const* d_in, const int* in_sizes, int n_in,
                              void* d_out, int out_size, void* d_ws, size_t ws_size,
                              hipStream_t stream) {
    const float* X       = (const float*)d_in[0];
    const int*   ranking = (const int*)d_in[1];
    const int*   choice  = (const int*)d_in[2];
    const int*   ncp     = (const int*)d_in[3];
    float*       ws      = (float*)d_ws;

    // ws: acc f32[4] | utab f32[512] | g2a u16[8192] | g2s u16[8192]
    float*          acc  = ws;
    float*          utab = ws + 4;
    unsigned short* g2a  = (unsigned short*)(ws + 4 + NROW);
    unsigned short* g2s  = g2a + 16 * 64 * 8;

    hipMemsetAsync(acc, 0, sizeof(float), stream);
    prep_kernel<<<dim3(1), dim3(512), 0, stream>>>(ranking, choice, ncp, g2a, g2s, utab);
    colpass<<<dim3(1024), dim3(256), 0, stream>>>(X, g2a, g2s, utab, acc);
    finalize<<<dim3(1), dim3(1), 0, stream>>>(acc, (float*)d_out);
}

// Round 11
// 92.333 us; speedup vs baseline: 1.2558x; 1.2558x over previous
//
#include <hip/hip_runtime.h>

// UPCLoss, algebraically reduced (validated R7-R10, absmax 0.0):
//   N^2*loss = sum_i u_i*||x_i||^2 - 2 * sum_{c,k} W[c][k]*S[c][k]
//   [W;S] = [G2 | onehot]^T (32x512) . X (512x65536)  (tall-skinny GEMM)
//   u_i   = sum_c cnt[c]*G2[i][c] + H[label_i],  H[c] = sum_i G2[i][c]
// R7-R10 all capped ~1.4 TB/s: 256B-per-row-visit column stripes thrash
// page translation. This round: 1KB segments, 256 cols/block, LDS-staged.

typedef float f32x4 __attribute__((ext_vector_type(4)));
typedef __bf16 bf16x8 __attribute__((ext_vector_type(8)));

constexpr int NROW = 512;
constexpr int KDIM = 65536;
constexpr int CH   = 256;               // cols per block
constexpr int NBLK = KDIM / CH;         // 256 blocks

__device__ __forceinline__ unsigned short bf16_bits(float v) {
    __bf16 h = (__bf16)v;
    unsigned short u;
    __builtin_memcpy(&u, &h, 2);
    return u;
}

__device__ __forceinline__ void gload16(const void* g, void* l) {
    __builtin_amdgcn_global_load_lds(
        (__attribute__((address_space(1))) void*)(g),
        (__attribute__((address_space(3))) void*)(l), 16, 0, 0);
}

// ---------- prep (identical to R9/R10, validated) ----------
// g2a/g2s: MFMA A-fragment tables [16 steps][64 lanes][8] bf16
//   g2a[(s*64+l)*8+t] = G2[s*32+(l>>4)*8+t][l&15]; g2s with onehot.
__global__ __launch_bounds__(512) void prep_kernel(const int* __restrict__ ranking,
                                                   const int* __restrict__ choice,
                                                   const int* __restrict__ ncp,
                                                   unsigned short* __restrict__ g2a,
                                                   unsigned short* __restrict__ g2s,
                                                   float* __restrict__ utab) {
    __shared__ float Hs[16];
    __shared__ int   cnt[16];
    int i = threadIdx.x;
    if (i < 16) { Hs[i] = 0.f; cnt[i] = 0; }
    __syncthreads();

    int rk[16];
#pragma unroll
    for (int q = 0; q < 16; ++q) rk[q] = ranking[i * 16 + q];
    int pos[16];
#pragma unroll
    for (int q = 0; q < 16; ++q) pos[rk[q]] = q;

    int   lbl = rk[0];
    float c   = (float)choice[i];
    float nc  = (float)(*ncp);
    atomicAdd(&cnt[lbl], 1);

    float grow[16];
#pragma unroll
    for (int q = 0; q < 16; ++q) {
        float r = (float)pos[q];
        float m = (r < c) ? (1.f - r / c) : (-(r - c + 1.f) / (nc - c));
        grow[q] = m * m;
        atomicAdd(&Hs[q], grow[q]);
    }

    int s = i >> 5, g = (i >> 3) & 3, t = i & 7;
#pragma unroll
    for (int q = 0; q < 16; ++q) {
        int idx = (s * 64 + (g << 4) + q) * 8 + t;
        g2a[idx] = bf16_bits(grow[q]);
        g2s[idx] = bf16_bits(q == lbl ? 1.f : 0.f);
    }
    __syncthreads();

    float u = 0.f;
#pragma unroll
    for (int q = 0; q < 16; ++q) u += (float)cnt[q] * grow[q];
    u += Hs[lbl];
    utab[i] = u;
}

// ---------- main pass: 256 blocks x 8 waves; block owns 256 columns ----------
__global__ __launch_bounds__(512, 1) void colpass(const float* __restrict__ X,
                                                  const unsigned short* __restrict__ g2a,
                                                  const unsigned short* __restrict__ g2s,
                                                  const float* __restrict__ utab,
                                                  float* __restrict__ acc) {
    __shared__ __align__(16) float lds[2][32 * CH];   // 2 x 32 KB

    // XCD swizzle (256 = 8*32): the 4 blocks sharing each 4KB page row-slice
    // land on the same XCD, so their concurrent streams merge in L2.
    int d   = blockIdx.x;
    int blk = (d & 7) * 32 + (d >> 3);
    int c0  = blk * CH;

    int t    = threadIdx.x;
    int lane = t & 63;
    int wv   = t >> 6;                   // 8 waves
    int rg   = lane >> 4;                // row-group 0..3 within K=32

    f32x4 accw[2] = {};
    f32x4 accs[2] = {};
    float t1 = 0.f;

    // stage rows [s*32, +32): wave wv stages rows wv*4..wv*4+3, one 1KB
    // contiguous segment per instr (64 lanes x 16B), linear LDS dest.
    auto stage = [&](int s, float* buf) {
#pragma unroll
        for (int rr = 0; rr < 4; ++rr) {
            int row = wv * 4 + rr;
            const float* g = X + (size_t)(s * 32 + row) * KDIM + c0 + lane * 4;
            gload16(g, (char*)buf + row * (CH * 4));
        }
    };

    stage(0, &lds[0][0]);
    __syncthreads();

    for (int s = 0; s < 16; ++s) {
        int cur = s & 1;
        if (s < 15) stage(s + 1, &lds[cur ^ 1][0]);

        const float* cb = &lds[cur][0];
        bf16x8 aw = *reinterpret_cast<const bf16x8*>(g2a + (s * 64 + lane) * 8);
        bf16x8 as = *reinterpret_cast<const bf16x8*>(g2s + (s * 64 + lane) * 8);
        float4 u0 = *reinterpret_cast<const float4*>(utab + s * 32 + rg * 8);
        float4 u1 = *reinterpret_cast<const float4*>(utab + s * 32 + rg * 8 + 4);

#pragma unroll
        for (int cg = 0; cg < 2; ++cg) {
            int cl = wv * 32 + cg * 16 + (lane & 15);
            float xv[8];
#pragma unroll
            for (int tt = 0; tt < 8; ++tt)
                xv[tt] = cb[(rg * 8 + tt) * CH + cl];

            bf16x8 xb;
#pragma unroll
            for (int tt = 0; tt < 8; ++tt) xb[tt] = (__bf16)xv[tt];

            accw[cg] = __builtin_amdgcn_mfma_f32_16x16x32_bf16(aw, xb, accw[cg], 0, 0, 0);
            accs[cg] = __builtin_amdgcn_mfma_f32_16x16x32_bf16(as, xb, accs[cg], 0, 0, 0);

            // t1 over this wave's unique (row, col) elements, reusing xv
            t1 = fmaf(u0.x, xv[0] * xv[0], t1);
            t1 = fmaf(u0.y, xv[1] * xv[1], t1);
            t1 = fmaf(u0.z, xv[2] * xv[2], t1);
            t1 = fmaf(u0.w, xv[3] * xv[3], t1);
            t1 = fmaf(u1.x, xv[4] * xv[4], t1);
            t1 = fmaf(u1.y, xv[5] * xv[5], t1);
            t1 = fmaf(u1.z, xv[6] * xv[6], t1);
            t1 = fmaf(u1.w, xv[7] * xv[7], t1);
        }

        __syncthreads();
    }

    // each (class c, col j) lives in exactly one lane devicewide
    float cross = 0.f;
#pragma unroll
    for (int cg = 0; cg < 2; ++cg)
        cross += accw[cg][0] * accs[cg][0] + accw[cg][1] * accs[cg][1]
               + accw[cg][2] * accs[cg][2] + accw[cg][3] * accs[cg][3];
    float local = fmaf(-2.f, cross, t1);

#pragma unroll
    for (int off = 32; off > 0; off >>= 1) local += __shfl_down(local, off);
    if (lane == 0) atomicAdd(acc, local);
}

__global__ void finalize(const float* __restrict__ acc, float* __restrict__ out) {
    out[0] = acc[0] * (1.f / ((float)NROW * (float)NROW));
}

extern "C" void kernel_launch(void* const* d_in, const int* in_sizes, int n_in,
                              void* d_out, int out_size, void* d_ws, size_t ws_size,
                              hipStream_t stream) {
    const float* X       = (const float*)d_in[0];
    const int*   ranking = (const int*)d_in[1];
    const int*   choice  = (const int*)d_in[2];
    const int*   ncp     = (const int*)d_in[3];
    float*       ws      = (float*)d_ws;

    // ws: acc f32[4] | utab f32[512] | g2a u16[8192] | g2s u16[8192]
    float*          acc  = ws;
    float*          utab = ws + 4;
    unsigned short* g2a  = (unsigned short*)(ws + 4 + NROW);
    unsigned short* g2s  = g2a + 16 * 64 * 8;

    hipMemsetAsync(acc, 0, sizeof(float), stream);
    prep_kernel<<<dim3(1), dim3(512), 0, stream>>>(ranking, choice, ncp, g2a, g2s, utab);
    colpass<<<dim3(NBLK), dim3(512), 0, stream>>>(X, g2a, g2s, utab, acc);
    finalize<<<dim3(1), dim3(1), 0, stream>>>(acc, (float*)d_out);
}